// Round 5
// baseline (195.077 us; speedup 1.0000x reference)
//
#include <hip/hip_runtime.h>
#include <hip/hip_bf16.h>
#include <math.h>

#define VN 50257   // vocab size
#define VD 512     // embedding dim
#define VP 128     // positives
#define VNEG 512   // negatives
#define VN_PAD 50260  // VN rounded up to multiple of 4

// ---------------- ws layout (floats) ----------------
#define OFF_CS   0                       // cs[4][VN_PAD]  shifted copies of center
#define OFF_WSH  (4 * VN_PAD)            // wsh[4][VN_PAD] shifted copies of w
#define OFF_VSH  (8 * VN_PAD)            // vsh[4][VN_PAD] shifted copies of v
#define OFF_IE   (12 * VN_PAD)           // ie[512]
#define OFF_SACC (12 * VN_PAD + 512)     // sacc[640]
#define WS_FULL_BYTES ((size_t)(12 * VN_PAD + 1160) * 4)

#define WCOLS 1024      // columns per w-block window
#define NWCB  50        // ceil(VN / WCOLS)
#define NWB2  100       // NWCB column-blocks x 2 d-halves
#define NVB   2048      // v-part blocks
#define SEG_LEN 12564   // n_ie/n_score segment length (multiple of 4)
#define NSB (4 * (VP + VNEG))   // n_score total blocks

// ---------------- helpers ----------------

__device__ __forceinline__ float block_reduce_sum_256(float val) {
    for (int off = 32; off > 0; off >>= 1)
        val += __shfl_down(val, off, 64);
    __shared__ float smem[4];
    int lane = threadIdx.x & 63;
    int wid  = threadIdx.x >> 6;
    if (lane == 0) smem[wid] = val;
    __syncthreads();
    if (wid == 0) {
        val = (lane < 4) ? smem[lane] : 0.f;
        for (int off = 2; off > 0; off >>= 1)
            val += __shfl_down(val, off, 64);
    }
    return val;  // valid in thread 0
}

__device__ __forceinline__ float log_sigmoid(float q) {
    return (q < 0.f) ? (q - log1pf(__expf(q))) : (-log1pf(__expf(-q)));
}

// Dot over n in [n0,n1) of row A (row misaligned by h head elements) against x,
// with xsh[k] = x[h+k] 16B-aligned. n0 multiple of 4. blockDim.x == 256.
__device__ __forceinline__ float seg_dot_shift(const float* __restrict__ Arow,
                                               const float* __restrict__ xsh,
                                               const float* __restrict__ x0,
                                               int h, int n0, int n1) {
    int t = threadIdx.x;
    float acc = 0.f;
    if (t < h && n0 + t < n1) acc += Arow[n0 + t] * x0[n0 + t];   // head
    int a0 = n0 + h;
    int nf4 = (n1 - a0) >> 2;
    const float4* A4 = (const float4*)(Arow + a0);   // 16B aligned
    const float4* X4 = (const float4*)(xsh + n0);    // 16B aligned
    #pragma unroll 4
    for (int i = t; i < nf4; i += 256) {
        float4 a = A4[i];
        float4 b = X4[i];
        acc += a.x * b.x + a.y * b.y + a.z * b.z + a.w * b.w;
    }
    int tail0 = a0 + (nf4 << 2);
    if (t < 4) {
        int n = tail0 + t;
        if (n < n1) acc += Arow[n] * x0[n];
    }
    return acc;
}

// ================= FULL (fast) PATH =================

// prep: build cs (4 shifted copies of center), zero wsh, ie, sacc
__global__ __launch_bounds__(256) void n_prep(const float* __restrict__ c,
                                              float* __restrict__ ws) {
    int i = blockIdx.x * 256 + threadIdx.x;
    if (i < 4 * VN_PAD) {
        int h = i / VN_PAD;
        int k = i - h * VN_PAD;
        ws[OFF_CS + i]  = (k < VN - h) ? c[h + k] : 0.f;
        ws[OFF_WSH + i] = 0.f;
    }
    if (i < 512) ws[OFF_IE + i] = 0.f;
    if (i < 640) ws[OFF_SACC + i] = 0.f;
}

// ie[d] += partial dot(IE[d,:], center) — 4 segments/row, 2048 blocks
__global__ __launch_bounds__(256) void n_ie(const float* __restrict__ IE,
                                            float* __restrict__ ws) {
    int b = blockIdx.x;
    int d = b >> 2;
    int s = b & 3;
    int n0 = s * SEG_LEN;
    int n1 = (s == 3) ? VN : n0 + SEG_LEN;
    int h = (4 - (d & 3)) & 3;             // (d*VN)%4 == d%4 since VN%4==1
    const float* Arow = IE + (size_t)d * VN;
    float acc = seg_dot_shift(Arow, ws + OFF_CS + h * VN_PAD, ws + OFF_CS, h, n0, n1);
    float sum = block_reduce_sum_256(acc);
    if (threadIdx.x == 0) atomicAdd(&ws[OFF_IE + d], sum);
}

// fused: blocks [0,NWB2) compute w += IE^T@ie via ROW-CONTIGUOUS float4 sweeps
//        (block owns a 1024-column window x 256 d-rows; R4's column-strided
//         walk was latency-bound at 1.1 TB/s);
//        blocks [NWB2,NWB2+NVB) compute v[n] = ie . OE[n,:].
__global__ __launch_bounds__(256) void n_wv(const float* __restrict__ IE,
                                            const float* __restrict__ OE,
                                            float* __restrict__ ws) {
    int t = threadIdx.x;
    if (blockIdx.x < NWB2) {
        __shared__ float ie_s[512];
        __shared__ float buf[WCOLS + 8];
        int cb  = blockIdx.x % NWCB;       // column block
        int dh  = blockIdx.x / NWCB;       // d half
        int c0  = cb * WCOLS;
        int dlo = dh * 256;
        for (int j = t; j < 512; j += 256) ie_s[j] = ws[OFF_IE + j];
        for (int j = t; j < WCOLS + 8; j += 256) buf[j] = 0.f;
        __syncthreads();

        float acc[7] = {0.f, 0.f, 0.f, 0.f, 0.f, 0.f, 0.f};
        bool full = (c0 + 1026 < VN);      // max col touched = c0+1026

        // class g: rows d = dlo+g+4k, row misalign -> col base offset hg=(4-g)&3.
        // acc[hg+j] maps to window position 4t+hg+j (static indices only).
#define WCLASS(g, hg) {                                                     \
        const float* p = IE + (size_t)(dlo + (g)) * VN + (c0 + (hg) + 4*t); \
        _Pragma("unroll 8")                                                 \
        for (int k = 0; k < 64; ++k) {                                      \
            float4 a = *(const float4*)p;                                   \
            float sv = ie_s[dlo + (g) + 4 * k];                             \
            acc[(hg) + 0] += sv * a.x; acc[(hg) + 1] += sv * a.y;           \
            acc[(hg) + 2] += sv * a.z; acc[(hg) + 3] += sv * a.w;           \
            p += (size_t)4 * VN;                                            \
        } }
#define WCLASSG(g, hg) {                                                    \
        int cb0 = c0 + (hg) + 4 * t;                                        \
        for (int k = 0; k < 64; ++k) {                                      \
            int d = dlo + (g) + 4 * k;                                      \
            float sv = ie_s[d];                                             \
            const float* row = IE + (size_t)d * VN;                         \
            if (cb0     < VN) acc[(hg) + 0] += sv * row[cb0];               \
            if (cb0 + 1 < VN) acc[(hg) + 1] += sv * row[cb0 + 1];           \
            if (cb0 + 2 < VN) acc[(hg) + 2] += sv * row[cb0 + 2];           \
            if (cb0 + 3 < VN) acc[(hg) + 3] += sv * row[cb0 + 3];           \
        } }
        if (full) {
            WCLASS(0, 0) WCLASS(1, 3) WCLASS(2, 2) WCLASS(3, 1)
        } else {
            WCLASSG(0, 0) WCLASSG(1, 3) WCLASSG(2, 2) WCLASSG(3, 1)
        }
#undef WCLASS
#undef WCLASSG

        // head columns [0,hg) of each class exist only in the cb==0 window
        if (cb == 0) {
            int g = t >> 6, lane = t & 63;
            int hg = (4 - g) & 3;
            if (lane < hg) {
                float ha = 0.f;
                for (int k = 0; k < 64; ++k) {
                    int d = dlo + g + 4 * k;
                    ha += ie_s[d] * IE[(size_t)d * VN + lane];
                }
                atomicAdd(&buf[lane], ha);
            }
        }

        #pragma unroll
        for (int j = 0; j < 7; ++j) atomicAdd(&buf[4 * t + j], acc[j]);
        __syncthreads();

        // write window into the 4 shifted w copies (wsh pre-zeroed by n_prep;
        // atomicAdd because the two d-halves and window overlaps both land here)
        for (int pos = t; pos < WCOLS + 7; pos += 256) {
            int col = c0 + pos;
            if (col >= VN) break;
            float s = buf[pos];
            #pragma unroll
            for (int hh = 0; hh < 4; ++hh)
                if (col >= hh)
                    atomicAdd(&ws[OFF_WSH + hh * VN_PAD + col - hh], s);
        }
    } else {
        // ---- v-part: one wave per row-pair, grid-stride ----
        int lane = t & 63;
        int gw = (blockIdx.x - NWB2) * 4 + (t >> 6);
        const int nW = NVB * 4;
        const float4* ie4 = (const float4*)(ws + OFF_IE);
        float4 e0 = ie4[lane];
        float4 e1 = ie4[64 + lane];
        for (int pr = gw; pr < (VN + 1) / 2; pr += nW) {
            int r = 2 * pr;
            bool two = (r + 1 < VN);
            const float4* row0 = (const float4*)(OE + (size_t)r * VD);
            float4 a0 = row0[lane];
            float4 a1 = row0[64 + lane];
            float p0 = a0.x * e0.x + a0.y * e0.y + a0.z * e0.z + a0.w * e0.w
                     + a1.x * e1.x + a1.y * e1.y + a1.z * e1.z + a1.w * e1.w;
            float p1 = 0.f;
            if (two) {
                const float4* row1 = row0 + 128;
                float4 b0 = row1[lane];
                float4 b1 = row1[64 + lane];
                p1 = b0.x * e0.x + b0.y * e0.y + b0.z * e0.z + b0.w * e0.w
                   + b1.x * e1.x + b1.y * e1.y + b1.z * e1.z + b1.w * e1.w;
            }
            #pragma unroll
            for (int off = 32; off > 0; off >>= 1) {
                p0 += __shfl_down(p0, off, 64);
                p1 += __shfl_down(p1, off, 64);
            }
            if (lane == 0) {
                #pragma unroll
                for (int h = 0; h < 4; ++h) {
                    if (r >= h)            ws[OFF_VSH + h * VN_PAD + r - h]     = p0;
                    if (two && r + 1 >= h) ws[OFF_VSH + h * VN_PAD + r + 1 - h] = p1;
                }
            }
        }
    }
}

// scores: 4 segments/row, 2560 blocks; partials into sacc via atomics.
// (NO fused finalize: contended counter + per-block fence cost 6x in R3.)
__global__ __launch_bounds__(256) void n_score(const float* __restrict__ PW,
                                               const float* __restrict__ NW,
                                               float* __restrict__ ws) {
    int b = blockIdx.x;
    int r = b >> 2;
    int s = b & 3;
    int n0 = s * SEG_LEN;
    int n1 = (s == 3) ? VN : n0 + SEG_LEN;
    int h = (4 - (r & 3)) & 3;
    const float* Arow;
    const float* xs;
    if (r < VP) { Arow = PW + (size_t)r * VN;        xs = ws + OFF_WSH; }
    else        { Arow = NW + (size_t)(r - VP) * VN; xs = ws + OFF_VSH; }
    float acc = seg_dot_shift(Arow, xs + h * VN_PAD, xs, h, n0, n1);
    float sum = block_reduce_sum_256(acc);
    if (threadIdx.x == 0) atomicAdd(&ws[OFF_SACC + r], sum);
}

__global__ __launch_bounds__(256) void n_final(const float* __restrict__ ws,
                                               float* __restrict__ out) {
    float acc = 0.f;
    for (int r = threadIdx.x; r < VP + VNEG; r += 256) {
        float s = ws[OFF_SACC + r];
        float q = (r < VP) ? s : -s;
        acc += log_sigmoid(q);
    }
    acc = block_reduce_sum_256(acc);
    if (threadIdx.x == 0) out[0] = -acc;
}

// ================= FALLBACK PATH (round-1, known-good) =================

__device__ __forceinline__ float row_dot_256(const float* __restrict__ A,
                                             const float* __restrict__ x,
                                             int mis) {
    int t = threadIdx.x;
    int h = (4 - mis) & 3;
    float acc = 0.f;
    if (t < h) acc += A[t] * x[t];
    int nf4 = (VN - h) >> 2;
    const float4* A4 = (const float4*)(A + h);
    for (int i = t; i < nf4; i += 256) {
        float4 a = A4[i];
        int nb = h + 4 * i;
        acc += a.x * x[nb] + a.y * x[nb + 1] + a.z * x[nb + 2] + a.w * x[nb + 3];
    }
    int tail0 = h + (nf4 << 2);
    int tr = t - h;
    if (tr >= 0 && tail0 + tr < VN)
        acc += A[tail0 + tr] * x[tail0 + tr];
    return acc;
}

__global__ void f_zero(float* __restrict__ w) {
    int i = blockIdx.x * blockDim.x + threadIdx.x;
    if (i < VN) w[i] = 0.f;
}

__global__ __launch_bounds__(256) void f_ie(const float* __restrict__ IE,
                                            const float* __restrict__ c,
                                            float* __restrict__ ie) {
    int d = blockIdx.x;
    float acc = row_dot_256(IE + (size_t)d * VN, c, d & 3);
    acc = block_reduce_sum_256(acc);
    if (threadIdx.x == 0) ie[d] = acc;
}

__global__ __launch_bounds__(256) void f_w(const float* __restrict__ IE,
                                           const float* __restrict__ ie,
                                           float* __restrict__ w) {
    int n = blockIdx.x * blockDim.x + threadIdx.x;
    if (n >= VN) return;
    int d0 = blockIdx.y * 64;
    const float* p = IE + (size_t)d0 * VN + n;
    float acc0 = 0.f, acc1 = 0.f;
    #pragma unroll 16
    for (int i = 0; i < 64; i += 2) {
        acc0 += ie[d0 + i]     * p[(size_t)i * VN];
        acc1 += ie[d0 + i + 1] * p[(size_t)(i + 1) * VN];
    }
    atomicAdd(&w[n], acc0 + acc1);
}

__global__ __launch_bounds__(256) void f_v(const float* __restrict__ OE,
                                           const float* __restrict__ ie,
                                           float* __restrict__ v) {
    int lane = threadIdx.x & 63;
    int gw   = blockIdx.x * (blockDim.x >> 6) + (threadIdx.x >> 6);
    int nW   = gridDim.x * (blockDim.x >> 6);
    const float4* ie4 = (const float4*)ie;
    float4 e0 = ie4[lane];
    float4 e1 = ie4[64 + lane];
    for (int r = gw; r < VN; r += nW) {
        const float4* row4 = (const float4*)(OE + (size_t)r * VD);
        float4 a0 = row4[lane];
        float4 a1 = row4[64 + lane];
        float p = a0.x * e0.x + a0.y * e0.y + a0.z * e0.z + a0.w * e0.w
                + a1.x * e1.x + a1.y * e1.y + a1.z * e1.z + a1.w * e1.w;
        for (int off = 32; off > 0; off >>= 1)
            p += __shfl_down(p, off, 64);
        if (lane == 0) v[r] = p;
    }
}

__global__ __launch_bounds__(256) void f_score(const float* __restrict__ PW,
                                               const float* __restrict__ NW,
                                               const float* __restrict__ w,
                                               const float* __restrict__ v,
                                               float* __restrict__ scores) {
    int r = blockIdx.x;
    const float* A;
    const float* x;
    if (r < VP) { A = PW + (size_t)r * VN;        x = w; }
    else        { A = NW + (size_t)(r - VP) * VN; x = v; }
    float acc = row_dot_256(A, x, r & 3);
    float s = block_reduce_sum_256(acc);
    if (threadIdx.x == 0) {
        float q = (r < VP) ? s : -s;
        scores[r] = log_sigmoid(q);
    }
}

__global__ __launch_bounds__(256) void f_final(const float* __restrict__ scores,
                                               float* __restrict__ out) {
    float acc = 0.f;
    for (int i = threadIdx.x; i < VP + VNEG; i += 256)
        acc += scores[i];
    acc = block_reduce_sum_256(acc);
    if (threadIdx.x == 0) out[0] = -acc;
}

// ---------------- launcher ----------------

extern "C" void kernel_launch(void* const* d_in, const int* in_sizes, int n_in,
                              void* d_out, int out_size, void* d_ws, size_t ws_size,
                              hipStream_t stream) {
    const float* center = (const float*)d_in[0];  // [VN]
    const float* PW     = (const float*)d_in[1];  // [VP, VN]
    const float* NW     = (const float*)d_in[2];  // [VNEG, VN]
    const float* IE     = (const float*)d_in[3];  // [VD, VN]
    const float* OE     = (const float*)d_in[4];  // [VN, VD]
    float* out = (float*)d_out;
    float* ws  = (float*)d_ws;
    dim3 blk(256);

    if (ws_size >= WS_FULL_BYTES) {
        n_prep <<<dim3((4 * VN_PAD + 255) / 256), blk, 0, stream>>>(center, ws);
        n_ie   <<<dim3(4 * VD),                   blk, 0, stream>>>(IE, ws);
        n_wv   <<<dim3(NWB2 + NVB),               blk, 0, stream>>>(IE, OE, ws);
        n_score<<<dim3(NSB),                      blk, 0, stream>>>(PW, NW, ws);
        n_final<<<dim3(1),                        blk, 0, stream>>>(ws, out);
    } else {
        float* ie     = ws;
        float* scores = ws + 512;
        float* w      = ws + 512 + 640;
        float* v      = ws + 512 + 640 + VN;
        f_zero <<<dim3((VN + 255) / 256), blk, 0, stream>>>(w);
        f_ie   <<<dim3(VD),              blk, 0, stream>>>(IE, center, ie);
        f_w    <<<dim3((VN + 255) / 256, VD / 64), blk, 0, stream>>>(IE, ie, w);
        f_v    <<<dim3(1024),            blk, 0, stream>>>(OE, ie, v);
        f_score<<<dim3(VP + VNEG),       blk, 0, stream>>>(PW, NW, w, v, scores);
        f_final<<<dim3(1),               blk, 0, stream>>>(scores, out);
    }
}

// Round 6
// 97.142 us; speedup vs baseline: 2.0082x; 2.0082x over previous
//
#include <hip/hip_runtime.h>
#include <hip/hip_bf16.h>
#include <math.h>

#define VN 50257   // vocab size
#define VD 512     // embedding dim
#define VP 128     // positives
#define VNEG 512   // negatives
#define VN_PAD 50260  // VN rounded up to multiple of 4

// ---------------- ws layout (floats) ----------------
#define OFF_CS   0                       // cs[4][VN_PAD]  shifted copies of center
#define OFF_WSH  (4 * VN_PAD)            // wsh[4][VN_PAD] shifted copies of w
#define OFF_VSH  (8 * VN_PAD)            // vsh[4][VN_PAD] shifted copies of v
#define OFF_IE   (12 * VN_PAD)           // ie[512]
#define OFF_SACC (12 * VN_PAD + 512)     // sacc[640]
#define WS_FULL_BYTES ((size_t)(12 * VN_PAD + 1160) * 4)

// w-part: column-owner blocks (64 cols each), d-split 2 for 2x waves.
// Lesson R4/R5: this stage is L3-LATENCY-bound; throughput ~ #outstanding
// loads ~ #waves. 1572 blocks (6288 waves) >> 100 blocks (400 waves).
#define WCB  786            // ceil(VN/64) column blocks
#define WDB  2              // d halves
#define WB3  (WCB * WDB)    // 1572 w-blocks
#define NVB  1536           // v-part blocks
#define SEG_LEN 12564       // n_ie/n_score segment length (multiple of 4)
#define NSB (4 * (VP + VNEG))   // n_score total blocks

// ---------------- helpers ----------------

__device__ __forceinline__ float block_reduce_sum_256(float val) {
    for (int off = 32; off > 0; off >>= 1)
        val += __shfl_down(val, off, 64);
    __shared__ float smem[4];
    int lane = threadIdx.x & 63;
    int wid  = threadIdx.x >> 6;
    if (lane == 0) smem[wid] = val;
    __syncthreads();
    if (wid == 0) {
        val = (lane < 4) ? smem[lane] : 0.f;
        for (int off = 2; off > 0; off >>= 1)
            val += __shfl_down(val, off, 64);
    }
    return val;  // valid in thread 0
}

__device__ __forceinline__ float log_sigmoid(float q) {
    return (q < 0.f) ? (q - log1pf(__expf(q))) : (-log1pf(__expf(-q)));
}

// Dot over n in [n0,n1) of row A (row misaligned by h head elements) against x,
// with xsh[k] = x[h+k] 16B-aligned. n0 multiple of 4. blockDim.x == 256.
__device__ __forceinline__ float seg_dot_shift(const float* __restrict__ Arow,
                                               const float* __restrict__ xsh,
                                               const float* __restrict__ x0,
                                               int h, int n0, int n1) {
    int t = threadIdx.x;
    float acc = 0.f;
    if (t < h && n0 + t < n1) acc += Arow[n0 + t] * x0[n0 + t];   // head
    int a0 = n0 + h;
    int nf4 = (n1 - a0) >> 2;
    const float4* A4 = (const float4*)(Arow + a0);   // 16B aligned
    const float4* X4 = (const float4*)(xsh + n0);    // 16B aligned
    #pragma unroll 4
    for (int i = t; i < nf4; i += 256) {
        float4 a = A4[i];
        float4 b = X4[i];
        acc += a.x * b.x + a.y * b.y + a.z * b.z + a.w * b.w;
    }
    int tail0 = a0 + (nf4 << 2);
    if (t < 4) {
        int n = tail0 + t;
        if (n < n1) acc += Arow[n] * x0[n];
    }
    return acc;
}

// ================= FULL (fast) PATH =================

// prep: build cs (4 shifted copies of center), zero wsh, ie, sacc
__global__ __launch_bounds__(256) void n_prep(const float* __restrict__ c,
                                              float* __restrict__ ws) {
    int i = blockIdx.x * 256 + threadIdx.x;
    if (i < 4 * VN_PAD) {
        int h = i / VN_PAD;
        int k = i - h * VN_PAD;
        ws[OFF_CS + i]  = (k < VN - h) ? c[h + k] : 0.f;
        ws[OFF_WSH + i] = 0.f;
    }
    if (i < 512) ws[OFF_IE + i] = 0.f;
    if (i < 640) ws[OFF_SACC + i] = 0.f;
}

// ie[d] += partial dot(IE[d,:], center) — 4 segments/row, 2048 blocks
__global__ __launch_bounds__(256) void n_ie(const float* __restrict__ IE,
                                            float* __restrict__ ws) {
    int b = blockIdx.x;
    int d = b >> 2;
    int s = b & 3;
    int n0 = s * SEG_LEN;
    int n1 = (s == 3) ? VN : n0 + SEG_LEN;
    int h = (4 - (d & 3)) & 3;             // (d*VN)%4 == d%4 since VN%4==1
    const float* Arow = IE + (size_t)d * VN;
    float acc = seg_dot_shift(Arow, ws + OFF_CS + h * VN_PAD, ws + OFF_CS, h, n0, n1);
    float sum = block_reduce_sum_256(acc);
    if (threadIdx.x == 0) atomicAdd(&ws[OFF_IE + d], sum);
}

// fused: blocks [0,WB3) compute w += IE^T@ie — column-owner, scalar loads,
//        many waves (latency-bound stage: throughput ~ #waves in flight);
//        blocks [WB3,WB3+NVB) compute v[n] = ie . OE[n,:] (HBM stream).
__global__ __launch_bounds__(256) void n_wv(const float* __restrict__ IE,
                                            const float* __restrict__ OE,
                                            float* __restrict__ ws) {
    int t = threadIdx.x;
    if (blockIdx.x < WB3) {
        // ---- w-part: block owns 64 columns x 256 d-rows ----
        __shared__ float ie_s[256];
        __shared__ float red[256];
        int cblk = blockIdx.x >> 1;        // column block 0..785
        int dh   = blockIdx.x & 1;         // d half
        int dlo  = dh * 256;
        ie_s[t] = ws[OFF_IE + dlo + t];
        __syncthreads();
        int lane = t & 63;
        int g    = t >> 6;                 // wave id: d-quarter within half
        int n    = cblk * 64 + lane;
        float acc0 = 0.f, acc1 = 0.f;
        if (n < VN) {
            const float* p = IE + (size_t)(dlo + g * 64) * VN + n;
            int dbase = g * 64;
            #pragma unroll 8
            for (int i = 0; i < 64; i += 2) {
                acc0 += ie_s[dbase + i]     * p[0];
                acc1 += ie_s[dbase + i + 1] * p[VN];
                p += (size_t)2 * VN;
            }
        }
        red[t] = acc0 + acc1;
        __syncthreads();
        if (t < 64) {
            int nn = cblk * 64 + t;
            if (nn < VN) {
                float s = red[t] + red[64 + t] + red[128 + t] + red[192 + t];
                #pragma unroll
                for (int hh = 0; hh < 4; ++hh)
                    if (nn >= hh)
                        atomicAdd(&ws[OFF_WSH + hh * VN_PAD + nn - hh], s);
            }
        }
    } else {
        // ---- v-part: one wave per row-pair, grid-stride ----
        int lane = t & 63;
        int gw = (blockIdx.x - WB3) * 4 + (t >> 6);
        const int nW = NVB * 4;
        const float4* ie4 = (const float4*)(ws + OFF_IE);
        float4 e0 = ie4[lane];
        float4 e1 = ie4[64 + lane];
        for (int pr = gw; pr < (VN + 1) / 2; pr += nW) {
            int r = 2 * pr;
            bool two = (r + 1 < VN);
            const float4* row0 = (const float4*)(OE + (size_t)r * VD);
            float4 a0 = row0[lane];
            float4 a1 = row0[64 + lane];
            float p0 = a0.x * e0.x + a0.y * e0.y + a0.z * e0.z + a0.w * e0.w
                     + a1.x * e1.x + a1.y * e1.y + a1.z * e1.z + a1.w * e1.w;
            float p1 = 0.f;
            if (two) {
                const float4* row1 = row0 + 128;
                float4 b0 = row1[lane];
                float4 b1 = row1[64 + lane];
                p1 = b0.x * e0.x + b0.y * e0.y + b0.z * e0.z + b0.w * e0.w
                   + b1.x * e1.x + b1.y * e1.y + b1.z * e1.z + b1.w * e1.w;
            }
            #pragma unroll
            for (int off = 32; off > 0; off >>= 1) {
                p0 += __shfl_down(p0, off, 64);
                p1 += __shfl_down(p1, off, 64);
            }
            if (lane == 0) {
                #pragma unroll
                for (int h = 0; h < 4; ++h) {
                    if (r >= h)            ws[OFF_VSH + h * VN_PAD + r - h]     = p0;
                    if (two && r + 1 >= h) ws[OFF_VSH + h * VN_PAD + r + 1 - h] = p1;
                }
            }
        }
    }
}

// scores: 4 segments/row, 2560 blocks; partials into sacc via atomics.
// (NO fused finalize: contended counter + per-block fence cost 6x in R3.)
__global__ __launch_bounds__(256) void n_score(const float* __restrict__ PW,
                                               const float* __restrict__ NW,
                                               float* __restrict__ ws) {
    int b = blockIdx.x;
    int r = b >> 2;
    int s = b & 3;
    int n0 = s * SEG_LEN;
    int n1 = (s == 3) ? VN : n0 + SEG_LEN;
    int h = (4 - (r & 3)) & 3;
    const float* Arow;
    const float* xs;
    if (r < VP) { Arow = PW + (size_t)r * VN;        xs = ws + OFF_WSH; }
    else        { Arow = NW + (size_t)(r - VP) * VN; xs = ws + OFF_VSH; }
    float acc = seg_dot_shift(Arow, xs + h * VN_PAD, xs, h, n0, n1);
    float sum = block_reduce_sum_256(acc);
    if (threadIdx.x == 0) atomicAdd(&ws[OFF_SACC + r], sum);
}

__global__ __launch_bounds__(256) void n_final(const float* __restrict__ ws,
                                               float* __restrict__ out) {
    float acc = 0.f;
    for (int r = threadIdx.x; r < VP + VNEG; r += 256) {
        float s = ws[OFF_SACC + r];
        float q = (r < VP) ? s : -s;
        acc += log_sigmoid(q);
    }
    acc = block_reduce_sum_256(acc);
    if (threadIdx.x == 0) out[0] = -acc;
}

// ================= FALLBACK PATH (round-1, known-good) =================

__device__ __forceinline__ float row_dot_256(const float* __restrict__ A,
                                             const float* __restrict__ x,
                                             int mis) {
    int t = threadIdx.x;
    int h = (4 - mis) & 3;
    float acc = 0.f;
    if (t < h) acc += A[t] * x[t];
    int nf4 = (VN - h) >> 2;
    const float4* A4 = (const float4*)(A + h);
    for (int i = t; i < nf4; i += 256) {
        float4 a = A4[i];
        int nb = h + 4 * i;
        acc += a.x * x[nb] + a.y * x[nb + 1] + a.z * x[nb + 2] + a.w * x[nb + 3];
    }
    int tail0 = h + (nf4 << 2);
    int tr = t - h;
    if (tr >= 0 && tail0 + tr < VN)
        acc += A[tail0 + tr] * x[tail0 + tr];
    return acc;
}

__global__ void f_zero(float* __restrict__ w) {
    int i = blockIdx.x * blockDim.x + threadIdx.x;
    if (i < VN) w[i] = 0.f;
}

__global__ __launch_bounds__(256) void f_ie(const float* __restrict__ IE,
                                            const float* __restrict__ c,
                                            float* __restrict__ ie) {
    int d = blockIdx.x;
    float acc = row_dot_256(IE + (size_t)d * VN, c, d & 3);
    acc = block_reduce_sum_256(acc);
    if (threadIdx.x == 0) ie[d] = acc;
}

__global__ __launch_bounds__(256) void f_w(const float* __restrict__ IE,
                                           const float* __restrict__ ie,
                                           float* __restrict__ w) {
    int n = blockIdx.x * blockDim.x + threadIdx.x;
    if (n >= VN) return;
    int d0 = blockIdx.y * 64;
    const float* p = IE + (size_t)d0 * VN + n;
    float acc0 = 0.f, acc1 = 0.f;
    #pragma unroll 16
    for (int i = 0; i < 64; i += 2) {
        acc0 += ie[d0 + i]     * p[(size_t)i * VN];
        acc1 += ie[d0 + i + 1] * p[(size_t)(i + 1) * VN];
    }
    atomicAdd(&w[n], acc0 + acc1);
}

__global__ __launch_bounds__(256) void f_v(const float* __restrict__ OE,
                                           const float* __restrict__ ie,
                                           float* __restrict__ v) {
    int lane = threadIdx.x & 63;
    int gw   = blockIdx.x * (blockDim.x >> 6) + (threadIdx.x >> 6);
    int nW   = gridDim.x * (blockDim.x >> 6);
    const float4* ie4 = (const float4*)ie;
    float4 e0 = ie4[lane];
    float4 e1 = ie4[64 + lane];
    for (int r = gw; r < VN; r += nW) {
        const float4* row4 = (const float4*)(OE + (size_t)r * VD);
        float4 a0 = row4[lane];
        float4 a1 = row4[64 + lane];
        float p = a0.x * e0.x + a0.y * e0.y + a0.z * e0.z + a0.w * e0.w
                + a1.x * e1.x + a1.y * e1.y + a1.z * e1.z + a1.w * e1.w;
        for (int off = 32; off > 0; off >>= 1)
            p += __shfl_down(p, off, 64);
        if (lane == 0) v[r] = p;
    }
}

__global__ __launch_bounds__(256) void f_score(const float* __restrict__ PW,
                                               const float* __restrict__ NW,
                                               const float* __restrict__ w,
                                               const float* __restrict__ v,
                                               float* __restrict__ scores) {
    int r = blockIdx.x;
    const float* A;
    const float* x;
    if (r < VP) { A = PW + (size_t)r * VN;        x = w; }
    else        { A = NW + (size_t)(r - VP) * VN; x = v; }
    float acc = row_dot_256(A, x, r & 3);
    float s = block_reduce_sum_256(acc);
    if (threadIdx.x == 0) {
        float q = (r < VP) ? s : -s;
        scores[r] = log_sigmoid(q);
    }
}

__global__ __launch_bounds__(256) void f_final(const float* __restrict__ scores,
                                               float* __restrict__ out) {
    float acc = 0.f;
    for (int i = threadIdx.x; i < VP + VNEG; i += 256)
        acc += scores[i];
    acc = block_reduce_sum_256(acc);
    if (threadIdx.x == 0) out[0] = -acc;
}

// ---------------- launcher ----------------

extern "C" void kernel_launch(void* const* d_in, const int* in_sizes, int n_in,
                              void* d_out, int out_size, void* d_ws, size_t ws_size,
                              hipStream_t stream) {
    const float* center = (const float*)d_in[0];  // [VN]
    const float* PW     = (const float*)d_in[1];  // [VP, VN]
    const float* NW     = (const float*)d_in[2];  // [VNEG, VN]
    const float* IE     = (const float*)d_in[3];  // [VD, VN]
    const float* OE     = (const float*)d_in[4];  // [VN, VD]
    float* out = (float*)d_out;
    float* ws  = (float*)d_ws;
    dim3 blk(256);

    if (ws_size >= WS_FULL_BYTES) {
        n_prep <<<dim3((4 * VN_PAD + 255) / 256), blk, 0, stream>>>(center, ws);
        n_ie   <<<dim3(4 * VD),                   blk, 0, stream>>>(IE, ws);
        n_wv   <<<dim3(WB3 + NVB),                blk, 0, stream>>>(IE, OE, ws);
        n_score<<<dim3(NSB),                      blk, 0, stream>>>(PW, NW, ws);
        n_final<<<dim3(1),                        blk, 0, stream>>>(ws, out);
    } else {
        float* ie     = ws;
        float* scores = ws + 512;
        float* w      = ws + 512 + 640;
        float* v      = ws + 512 + 640 + VN;
        f_zero <<<dim3((VN + 255) / 256), blk, 0, stream>>>(w);
        f_ie   <<<dim3(VD),              blk, 0, stream>>>(IE, center, ie);
        f_w    <<<dim3((VN + 255) / 256, VD / 64), blk, 0, stream>>>(IE, ie, w);
        f_v    <<<dim3(1024),            blk, 0, stream>>>(OE, ie, v);
        f_score<<<dim3(VP + VNEG),       blk, 0, stream>>>(PW, NW, w, v, scores);
        f_final<<<dim3(1),               blk, 0, stream>>>(scores, out);
    }
}

// Round 7
// 93.173 us; speedup vs baseline: 2.0937x; 1.0426x over previous
//
#include <hip/hip_runtime.h>
#include <hip/hip_bf16.h>
#include <math.h>

#define VN 50257   // vocab size
#define VD 512     // embedding dim
#define VP 128     // positives
#define VNEG 512   // negatives
#define VN_PAD 50260  // VN rounded up to multiple of 4

// ---------------- ws layout (floats) ----------------
#define OFF_CS   0                       // cs[4][VN_PAD]  shifted copies of center
#define OFF_WSH  (4 * VN_PAD)            // wsh[4][VN_PAD] shifted copies of w
#define OFF_VSH  (8 * VN_PAD)            // vsh[4][VN_PAD] shifted copies of v
#define OFF_IE   (12 * VN_PAD)           // ie[512]
#define OFF_SACC (12 * VN_PAD + 512)     // sacc[640]
#define WS_FULL_BYTES ((size_t)(12 * VN_PAD + 1160) * 4)

// w-part: column-owner blocks (64 cols each), d-split 2.
// R4/R5 lesson: stage is L3-latency-bound; throughput = in-flight bytes /
// latency. R6 lesson: per-wave ILP matters too — compiler kept only ~2-4
// loads in flight (n_wv ~57.6us hidden under the 58us harness fills).
// Fix: explicit 32-deep register batch per wave.
#define WCB  786            // ceil(VN/64) column blocks
#define WDB  2              // d halves
#define WB3  (WCB * WDB)    // 1572 w-blocks
#define NVB  1536           // v-part blocks (dispatched FIRST: HBM stream)
#define SEG_LEN 12564       // n_ie/n_score segment length (multiple of 4)
#define NSB (4 * (VP + VNEG))   // n_score total blocks

// ---------------- helpers ----------------

__device__ __forceinline__ float block_reduce_sum_256(float val) {
    for (int off = 32; off > 0; off >>= 1)
        val += __shfl_down(val, off, 64);
    __shared__ float smem[4];
    int lane = threadIdx.x & 63;
    int wid  = threadIdx.x >> 6;
    if (lane == 0) smem[wid] = val;
    __syncthreads();
    if (wid == 0) {
        val = (lane < 4) ? smem[lane] : 0.f;
        for (int off = 2; off > 0; off >>= 1)
            val += __shfl_down(val, off, 64);
    }
    return val;  // valid in thread 0
}

__device__ __forceinline__ float log_sigmoid(float q) {
    return (q < 0.f) ? (q - log1pf(__expf(q))) : (-log1pf(__expf(-q)));
}

// Dot over n in [n0,n1) of row A (row misaligned by h head elements) against x,
// with xsh[k] = x[h+k] 16B-aligned. n0 multiple of 4. blockDim.x == 256.
__device__ __forceinline__ float seg_dot_shift(const float* __restrict__ Arow,
                                               const float* __restrict__ xsh,
                                               const float* __restrict__ x0,
                                               int h, int n0, int n1) {
    int t = threadIdx.x;
    float acc = 0.f;
    if (t < h && n0 + t < n1) acc += Arow[n0 + t] * x0[n0 + t];   // head
    int a0 = n0 + h;
    int nf4 = (n1 - a0) >> 2;
    const float4* A4 = (const float4*)(Arow + a0);   // 16B aligned
    const float4* X4 = (const float4*)(xsh + n0);    // 16B aligned
    #pragma unroll 4
    for (int i = t; i < nf4; i += 256) {
        float4 a = A4[i];
        float4 b = X4[i];
        acc += a.x * b.x + a.y * b.y + a.z * b.z + a.w * b.w;
    }
    int tail0 = a0 + (nf4 << 2);
    if (t < 4) {
        int n = tail0 + t;
        if (n < n1) acc += Arow[n] * x0[n];
    }
    return acc;
}

// ================= FULL (fast) PATH =================

// prep: build cs (4 shifted copies of center), zero wsh, ie, sacc
__global__ __launch_bounds__(256) void n_prep(const float* __restrict__ c,
                                              float* __restrict__ ws) {
    int i = blockIdx.x * 256 + threadIdx.x;
    if (i < 4 * VN_PAD) {
        int h = i / VN_PAD;
        int k = i - h * VN_PAD;
        ws[OFF_CS + i]  = (k < VN - h) ? c[h + k] : 0.f;
        ws[OFF_WSH + i] = 0.f;
    }
    if (i < 512) ws[OFF_IE + i] = 0.f;
    if (i < 640) ws[OFF_SACC + i] = 0.f;
}

// ie[d] += partial dot(IE[d,:], center) — 4 segments/row, 2048 blocks
__global__ __launch_bounds__(256) void n_ie(const float* __restrict__ IE,
                                            float* __restrict__ ws) {
    int b = blockIdx.x;
    int d = b >> 2;
    int s = b & 3;
    int n0 = s * SEG_LEN;
    int n1 = (s == 3) ? VN : n0 + SEG_LEN;
    int h = (4 - (d & 3)) & 3;             // (d*VN)%4 == d%4 since VN%4==1
    const float* Arow = IE + (size_t)d * VN;
    float acc = seg_dot_shift(Arow, ws + OFF_CS + h * VN_PAD, ws + OFF_CS, h, n0, n1);
    float sum = block_reduce_sum_256(acc);
    if (threadIdx.x == 0) atomicAdd(&ws[OFF_IE + d], sum);
}

// fused: blocks [0,NVB) compute v[n] = ie . OE[n,:] (HBM stream, first);
//        blocks [NVB,NVB+WB3) compute w += IE^T@ie (L3 re-read, 32-deep MLP).
__global__ __launch_bounds__(256) void n_wv(const float* __restrict__ IE,
                                            const float* __restrict__ OE,
                                            float* __restrict__ ws) {
    int t = threadIdx.x;
    if (blockIdx.x >= NVB) {
        // ---- w-part: block owns 64 columns x 256 d-rows ----
        __shared__ float ie_s[256];
        __shared__ float red[256];
        int wb   = blockIdx.x - NVB;
        int cblk = wb >> 1;                // column block 0..785
        int dh   = wb & 1;                 // d half
        int dlo  = dh * 256;
        ie_s[t] = ws[OFF_IE + dlo + t];
        __syncthreads();
        int lane = t & 63;
        int g    = t >> 6;                 // wave id: d-quarter within half
        int n    = cblk * 64 + lane;
        float acc = 0.f;
        if (n < VN) {
            const float* p = IE + (size_t)(dlo + g * 64) * VN + n;
            int dbase = g * 64;
            // 32 independent loads in flight, twice (Little's law: need
            // ~6 MB in flight chip-wide to saturate L3; 2-4 was ~3 MB)
            float va[32];
            #pragma unroll
            for (int j = 0; j < 32; ++j) va[j] = p[(size_t)j * VN];
            #pragma unroll
            for (int j = 0; j < 32; ++j) acc += ie_s[dbase + j] * va[j];
            p += (size_t)32 * VN;
            #pragma unroll
            for (int j = 0; j < 32; ++j) va[j] = p[(size_t)j * VN];
            #pragma unroll
            for (int j = 0; j < 32; ++j) acc += ie_s[dbase + 32 + j] * va[j];
        }
        red[t] = acc;
        __syncthreads();
        if (t < 64) {
            int nn = cblk * 64 + t;
            if (nn < VN) {
                float s = red[t] + red[64 + t] + red[128 + t] + red[192 + t];
                #pragma unroll
                for (int hh = 0; hh < 4; ++hh)
                    if (nn >= hh)
                        atomicAdd(&ws[OFF_WSH + hh * VN_PAD + nn - hh], s);
            }
        }
    } else {
        // ---- v-part: one wave per row-pair, grid-stride ----
        int lane = t & 63;
        int gw = blockIdx.x * 4 + (t >> 6);
        const int nW = NVB * 4;
        const float4* ie4 = (const float4*)(ws + OFF_IE);
        float4 e0 = ie4[lane];
        float4 e1 = ie4[64 + lane];
        for (int pr = gw; pr < (VN + 1) / 2; pr += nW) {
            int r = 2 * pr;
            bool two = (r + 1 < VN);
            const float4* row0 = (const float4*)(OE + (size_t)r * VD);
            float4 a0 = row0[lane];
            float4 a1 = row0[64 + lane];
            float p0 = a0.x * e0.x + a0.y * e0.y + a0.z * e0.z + a0.w * e0.w
                     + a1.x * e1.x + a1.y * e1.y + a1.z * e1.z + a1.w * e1.w;
            float p1 = 0.f;
            if (two) {
                const float4* row1 = row0 + 128;
                float4 b0 = row1[lane];
                float4 b1 = row1[64 + lane];
                p1 = b0.x * e0.x + b0.y * e0.y + b0.z * e0.z + b0.w * e0.w
                   + b1.x * e1.x + b1.y * e1.y + b1.z * e1.z + b1.w * e1.w;
            }
            #pragma unroll
            for (int off = 32; off > 0; off >>= 1) {
                p0 += __shfl_down(p0, off, 64);
                p1 += __shfl_down(p1, off, 64);
            }
            if (lane == 0) {
                #pragma unroll
                for (int h = 0; h < 4; ++h) {
                    if (r >= h)            ws[OFF_VSH + h * VN_PAD + r - h]     = p0;
                    if (two && r + 1 >= h) ws[OFF_VSH + h * VN_PAD + r + 1 - h] = p1;
                }
            }
        }
    }
}

// scores: 4 segments/row, 2560 blocks; partials into sacc via atomics.
// (NO fused finalize: contended counter + per-block fence cost 6x in R3.)
__global__ __launch_bounds__(256) void n_score(const float* __restrict__ PW,
                                               const float* __restrict__ NW,
                                               float* __restrict__ ws) {
    int b = blockIdx.x;
    int r = b >> 2;
    int s = b & 3;
    int n0 = s * SEG_LEN;
    int n1 = (s == 3) ? VN : n0 + SEG_LEN;
    int h = (4 - (r & 3)) & 3;
    const float* Arow;
    const float* xs;
    if (r < VP) { Arow = PW + (size_t)r * VN;        xs = ws + OFF_WSH; }
    else        { Arow = NW + (size_t)(r - VP) * VN; xs = ws + OFF_VSH; }
    float acc = seg_dot_shift(Arow, xs + h * VN_PAD, xs, h, n0, n1);
    float sum = block_reduce_sum_256(acc);
    if (threadIdx.x == 0) atomicAdd(&ws[OFF_SACC + r], sum);
}

__global__ __launch_bounds__(256) void n_final(const float* __restrict__ ws,
                                               float* __restrict__ out) {
    float acc = 0.f;
    for (int r = threadIdx.x; r < VP + VNEG; r += 256) {
        float s = ws[OFF_SACC + r];
        float q = (r < VP) ? s : -s;
        acc += log_sigmoid(q);
    }
    acc = block_reduce_sum_256(acc);
    if (threadIdx.x == 0) out[0] = -acc;
}

// ================= FALLBACK PATH (round-1, known-good) =================

__device__ __forceinline__ float row_dot_256(const float* __restrict__ A,
                                             const float* __restrict__ x,
                                             int mis) {
    int t = threadIdx.x;
    int h = (4 - mis) & 3;
    float acc = 0.f;
    if (t < h) acc += A[t] * x[t];
    int nf4 = (VN - h) >> 2;
    const float4* A4 = (const float4*)(A + h);
    for (int i = t; i < nf4; i += 256) {
        float4 a = A4[i];
        int nb = h + 4 * i;
        acc += a.x * x[nb] + a.y * x[nb + 1] + a.z * x[nb + 2] + a.w * x[nb + 3];
    }
    int tail0 = h + (nf4 << 2);
    int tr = t - h;
    if (tr >= 0 && tail0 + tr < VN)
        acc += A[tail0 + tr] * x[tail0 + tr];
    return acc;
}

__global__ void f_zero(float* __restrict__ w) {
    int i = blockIdx.x * blockDim.x + threadIdx.x;
    if (i < VN) w[i] = 0.f;
}

__global__ __launch_bounds__(256) void f_ie(const float* __restrict__ IE,
                                            const float* __restrict__ c,
                                            float* __restrict__ ie) {
    int d = blockIdx.x;
    float acc = row_dot_256(IE + (size_t)d * VN, c, d & 3);
    acc = block_reduce_sum_256(acc);
    if (threadIdx.x == 0) ie[d] = acc;
}

__global__ __launch_bounds__(256) void f_w(const float* __restrict__ IE,
                                           const float* __restrict__ ie,
                                           float* __restrict__ w) {
    int n = blockIdx.x * blockDim.x + threadIdx.x;
    if (n >= VN) return;
    int d0 = blockIdx.y * 64;
    const float* p = IE + (size_t)d0 * VN + n;
    float acc0 = 0.f, acc1 = 0.f;
    #pragma unroll 16
    for (int i = 0; i < 64; i += 2) {
        acc0 += ie[d0 + i]     * p[(size_t)i * VN];
        acc1 += ie[d0 + i + 1] * p[(size_t)(i + 1) * VN];
    }
    atomicAdd(&w[n], acc0 + acc1);
}

__global__ __launch_bounds__(256) void f_v(const float* __restrict__ OE,
                                           const float* __restrict__ ie,
                                           float* __restrict__ v) {
    int lane = threadIdx.x & 63;
    int gw   = blockIdx.x * (blockDim.x >> 6) + (threadIdx.x >> 6);
    int nW   = gridDim.x * (blockDim.x >> 6);
    const float4* ie4 = (const float4*)ie;
    float4 e0 = ie4[lane];
    float4 e1 = ie4[64 + lane];
    for (int r = gw; r < VN; r += nW) {
        const float4* row4 = (const float4*)(OE + (size_t)r * VD);
        float4 a0 = row4[lane];
        float4 a1 = row4[64 + lane];
        float p = a0.x * e0.x + a0.y * e0.y + a0.z * e0.z + a0.w * e0.w
                + a1.x * e1.x + a1.y * e1.y + a1.z * e1.z + a1.w * e1.w;
        for (int off = 32; off > 0; off >>= 1)
            p += __shfl_down(p, off, 64);
        if (lane == 0) v[r] = p;
    }
}

__global__ __launch_bounds__(256) void f_score(const float* __restrict__ PW,
                                               const float* __restrict__ NW,
                                               const float* __restrict__ w,
                                               const float* __restrict__ v,
                                               float* __restrict__ scores) {
    int r = blockIdx.x;
    const float* A;
    const float* x;
    if (r < VP) { A = PW + (size_t)r * VN;        x = w; }
    else        { A = NW + (size_t)(r - VP) * VN; x = v; }
    float acc = row_dot_256(A, x, r & 3);
    float s = block_reduce_sum_256(acc);
    if (threadIdx.x == 0) {
        float q = (r < VP) ? s : -s;
        scores[r] = log_sigmoid(q);
    }
}

__global__ __launch_bounds__(256) void f_final(const float* __restrict__ scores,
                                               float* __restrict__ out) {
    float acc = 0.f;
    for (int i = threadIdx.x; i < VP + VNEG; i += 256)
        acc += scores[i];
    acc = block_reduce_sum_256(acc);
    if (threadIdx.x == 0) out[0] = -acc;
}

// ---------------- launcher ----------------

extern "C" void kernel_launch(void* const* d_in, const int* in_sizes, int n_in,
                              void* d_out, int out_size, void* d_ws, size_t ws_size,
                              hipStream_t stream) {
    const float* center = (const float*)d_in[0];  // [VN]
    const float* PW     = (const float*)d_in[1];  // [VP, VN]
    const float* NW     = (const float*)d_in[2];  // [VNEG, VN]
    const float* IE     = (const float*)d_in[3];  // [VD, VN]
    const float* OE     = (const float*)d_in[4];  // [VN, VD]
    float* out = (float*)d_out;
    float* ws  = (float*)d_ws;
    dim3 blk(256);

    if (ws_size >= WS_FULL_BYTES) {
        n_prep <<<dim3((4 * VN_PAD + 255) / 256), blk, 0, stream>>>(center, ws);
        n_ie   <<<dim3(4 * VD),                   blk, 0, stream>>>(IE, ws);
        n_wv   <<<dim3(NVB + WB3),                blk, 0, stream>>>(IE, OE, ws);
        n_score<<<dim3(NSB),                      blk, 0, stream>>>(PW, NW, ws);
        n_final<<<dim3(1),                        blk, 0, stream>>>(ws, out);
    } else {
        float* ie     = ws;
        float* scores = ws + 512;
        float* w      = ws + 512 + 640;
        float* v      = ws + 512 + 640 + VN;
        f_zero <<<dim3((VN + 255) / 256), blk, 0, stream>>>(w);
        f_ie   <<<dim3(VD),              blk, 0, stream>>>(IE, center, ie);
        f_w    <<<dim3((VN + 255) / 256, VD / 64), blk, 0, stream>>>(IE, ie, w);
        f_v    <<<dim3(1024),            blk, 0, stream>>>(OE, ie, v);
        f_score<<<dim3(VP + VNEG),       blk, 0, stream>>>(PW, NW, w, v, scores);
        f_final<<<dim3(1),               blk, 0, stream>>>(scores, out);
    }
}